// Round 9
// baseline (1436.820 us; speedup 1.0000x reference)
//
#include <hip/hip_runtime.h>
#include <math.h>

// Problem constants (fixed by setup_inputs)
constexpr int B    = 2;
constexpr int W    = 16;
constexpr int N    = 1000;
constexpr int FIN  = 16;
constexpr int E    = 16000;
constexpr int DE   = 8;
constexpr int H    = 128;   // hidden
constexpr int L    = 3;
// Window pruning: temporal edges go t -> t+1 and head reads only w=15;
// 3 layers => only global windows 12..15 matter.
constexpr int WL   = 4;          // local windows kept (global 12..15)
constexpr int W0G  = 12;         // first kept global window
constexpr int RPB  = WL * N;     // rows per batch = 4000
constexpr int ROWS = B * RPB;    // 8000
constexpr int NMAT = 12;         // transposed mats: (q,k,v,o) x 3 layers
constexpr int GRID = 768;        // <= guaranteed co-resident (4 blocks/CU x 256 CUs = 1024)

struct KParams {
  const float* xw; const int* ei; const float* ea;
  const float* in_w; const float* in_b;
  const float* qw; const float* qb; const float* kw; const float* kb;
  const float* vw; const float* vb; const float* fw; const float* fb;
  const float* ow; const float* ob; const float* lng; const float* lnb;
  const float* hw; const float* hb; float* out;
  float* x; float* x2; float* Qb; float* Kb; float* Vb;
  float* wTp; unsigned int* filmh; float* meanea; unsigned int* bar;
  int* offs; int* cursor; int2* csr;
};

__device__ __forceinline__ float dot4(float4 a, float4 b) {
  return a.x * b.x + a.y * b.y + a.z * b.z + a.w * b.w;
}
// DPP quad-perm butterfly adds (VALU pipe, not DS)
__device__ __forceinline__ float dpp_add_xor1(float x) {
  int y = __builtin_amdgcn_update_dpp(0, __float_as_int(x), 0xB1, 0xF, 0xF, true);
  return x + __int_as_float(y);
}
__device__ __forceinline__ float dpp_add_xor2(float x) {
  int y = __builtin_amdgcn_update_dpp(0, __float_as_int(x), 0x4E, 0xF, 0xF, true);
  return x + __int_as_float(y);
}
__device__ __forceinline__ float headSum32(float p) {
  p = dpp_add_xor1(p);
  p = dpp_add_xor2(p);
  p += __shfl_xor(p, 4);
  p += __shfl_xor(p, 8);
  p += __shfl_xor(p, 16);
  return p;
}

// Software grid barrier: monotone counter, device-scope atomics, bounded spin.
// All GRID blocks are co-resident by construction (launch_bounds + GRID <= capacity).
__device__ __forceinline__ void gbar(unsigned int* ctr, unsigned int target) {
  __syncthreads();
  if (threadIdx.x == 0) {
    __threadfence();  // release all prior global writes
    __hip_atomic_fetch_add(ctr, 1u, __ATOMIC_RELEASE, __HIP_MEMORY_SCOPE_AGENT);
    unsigned int spins = 0;
    while (__hip_atomic_load(ctr, __ATOMIC_ACQUIRE, __HIP_MEMORY_SCOPE_AGENT) < target) {
      if (++spins > 5000000u) break;  // bail instead of hanging the bench
      __builtin_amdgcn_s_sleep(8);
    }
  }
  __syncthreads();
  __threadfence();  // acquire side for all threads
}

union SmemU {
  float xs[16][H];                                        // gemm stage: 8 KB
  struct { float xwS[64][FIN]; float inS[FIN][H]; } ip;   // inproj: 12 KB
  struct { int cnt[1024]; int sT[256]; } sc;              // scan: 5 KB
  struct { float sab[2][H]; float red[2][2]; } at;        // attn: 1 KB
  float sbuf[256];                                        // easum: 1 KB
};

// sum over one 128-thread half-block (2 waves)
__device__ __forceinline__ float halfSum(float v, int half, int t, float (*red)[2]) {
  #pragma unroll
  for (int off = 32; off >= 1; off >>= 1) v += __shfl_xor(v, off);
  int w = (t >> 6) & 1;
  __syncthreads();
  if ((t & 63) == 0) red[half][w] = v;
  __syncthreads();
  return red[half][0] + red[half][1];
}

__global__ __launch_bounds__(256, 4) void k_mega(KParams p) {
  __shared__ SmemU sm;
  const int bid = blockIdx.x;
  const int t = threadIdx.x;
  const int GD = gridDim.x;
  unsigned int bno = 0;  // barrier sequence number

  // ================= P0: scan | weight transpose | easum | input proj =================
  if (bid == 0) {
    // ---- count + scan (CSR offsets + cursor) ----
    int* cnt = sm.sc.cnt;
    for (int i = t; i < 1024; i += 256) cnt[i] = 0;
    __syncthreads();
    for (int e = t; e < E; e += 256) atomicAdd(&cnt[p.ei[E + e]], 1);
    __syncthreads();
    int idx0 = t * 4;
    int c0 = cnt[idx0], c1 = cnt[idx0 + 1], c2 = cnt[idx0 + 2], c3 = cnt[idx0 + 3];
    int run = c0 + c1 + c2 + c3;
    int* sT = sm.sc.sT;
    sT[t] = run;
    __syncthreads();
    for (int st = 1; st < 256; st <<= 1) {
      int add = (t >= st) ? sT[t - st] : 0;
      __syncthreads();
      sT[t] += add;
      __syncthreads();
    }
    int excl = sT[t] - run;
    int pos = excl;
    int cs[4] = {c0, c1, c2, c3};
    #pragma unroll
    for (int j = 0; j < 4; j++) {
      int i = idx0 + j;
      if (i < N) { p.offs[i + 1] = pos + cs[j]; p.cursor[i] = pos; }
      pos += cs[j];
    }
    if (t == 0) p.offs[0] = 0;
  } else if (bid < 49) {
    // ---- weight transpose into k-packed layout (48 * 1024 float4 = exact) ----
    int u0 = (bid - 1) * 1024;
    #pragma unroll
    for (int q = 0; q < 4; q++) {
      int o = u0 + q * 256 + t;
      int mat = o >> 12, rem = o & 4095;
      int kk4 = rem >> 7, c = rem & 127;
      int l = mat >> 2, mm = mat & 3;
      const float* src = ((mm == 0) ? p.qw : (mm == 1) ? p.kw : (mm == 2) ? p.vw : p.ow)
                         + (long)l * H * H;
      int k0 = kk4 * 4;
      float4 v4 = make_float4(src[(k0 + 0) * H + c], src[(k0 + 1) * H + c],
                              src[(k0 + 2) * H + c], src[(k0 + 3) * H + c]);
      ((float4*)p.wTp)[o] = v4;
    }
  } else if (bid < 81) {
    // ---- ea column sums (32 blocks) ----
    int eb = bid - 49;
    int d = t & 7, g = t >> 3;
    float s = 0.f;
    for (int e = eb * 32 + g; e < E; e += 32 * 32) s += p.ea[e * DE + d];
    sm.sbuf[t] = s;
    __syncthreads();
    for (int st = 16; st >= 1; st >>= 1) {
      if (g < st) sm.sbuf[g * 8 + d] += sm.sbuf[(g + st) * 8 + d];
      __syncthreads();
    }
    if (g == 0) atomicAdd(&p.meanea[d], sm.sbuf[d]);
  } else if (bid < 81 + 126) {
    // ---- input projection: x = xw @ in_w + in_b (64-row tiles) ----
    int bi = bid - 81;
    int b = bi / 63, tt = bi % 63;
    int lr0 = tt * 64;
    for (int i = t; i < 64 * FIN; i += 256) {
      int r = i >> 4, k = i & 15;
      int lr = lr0 + r;
      float val = 0.f;
      if (lr < RPB) {
        int wl = lr / N, n = lr % N;
        val = p.xw[(((long)b * W + (W0G + wl)) * N + n) * FIN + k];
      }
      sm.ip.xwS[r][k] = val;
    }
    for (int i = t; i < FIN * H; i += 256) sm.ip.inS[i >> 7][i & 127] = p.in_w[i];
    __syncthreads();
    #pragma unroll
    for (int qi = 0; qi < 8; qi++) {
      int idx = t + qi * 256;
      int r = idx >> 5, cq = idx & 31;
      int lr = lr0 + r;
      if (lr < RPB) {
        float4 acc = *(const float4*)(p.in_b + cq * 4);
        #pragma unroll
        for (int k = 0; k < FIN; k++) {
          float xv = sm.ip.xwS[r][k];
          float4 w4 = *(const float4*)(&sm.ip.inS[k][cq * 4]);
          acc.x += xv * w4.x; acc.y += xv * w4.y; acc.z += xv * w4.z; acc.w += xv * w4.w;
        }
        *(float4*)(p.x + ((long)b * RPB + lr) * H + cq * 4) = acc;
      }
    }
  }
  gbar(p.bar, ++bno * GD);

  // ================= layer loop =================
  float* xa = p.x;
  float* xb = p.x2;
  for (int l = 0; l < L; l++) {
    int in_lo = l, out_lo = l + 1;
    int rows_pb = (WL - in_lo) * N;
    int tiles = (rows_pb + 15) / 16;
    int nG = 3 * B * tiles;
    int nFilm = (E + 1 + 7) / 8;       // 2001
    int nFill = (l == 0) ? (E + 255) / 256 : 0;
    int nU = nG + nFilm + nFill;
    for (int u = bid; u < nU; u += GD) {
      if (u < nG) {
        // ---- QKV GEMM: 16 rows x 128 cols, X in LDS, 2x4 reg tile ----
        int m = u / (B * tiles);
        int r2 = u % (B * tiles);
        int bb = r2 / tiles, tt = r2 % tiles;
        const float* bm = ((m == 0) ? p.qb : (m == 1) ? p.kb : p.vb) + l * H;
        float* Cm = (m == 0) ? p.Qb : (m == 1) ? p.Kb : p.Vb;
        const float4* wp = (const float4*)p.wTp + (long)(l * 4 + m) * 32 * H;
        int lr0 = tt * 16;
        long grow0 = (long)bb * RPB + in_lo * N + lr0;
        #pragma unroll
        for (int q = 0; q < 2; q++) {
          int idx = t + q * 256;
          int r = idx >> 5, c4 = idx & 31;
          float4 v4 = make_float4(0.f, 0.f, 0.f, 0.f);
          if (lr0 + r < rows_pb) v4 = *(const float4*)(xa + (grow0 + r) * H + c4 * 4);
          *(float4*)&sm.xs[r][c4 * 4] = v4;
        }
        __syncthreads();
        int cg_ = t & 31, rg = t >> 5;
        float4 bias4 = *(const float4*)(bm + cg_ * 4);
        float4 acc0 = bias4, acc1 = bias4;
        #pragma unroll 4
        for (int kk4 = 0; kk4 < 32; kk4++) {
          const float4* wr = wp + kk4 * H + cg_ * 4;
          float4 w0 = wr[0], w1 = wr[1], w2 = wr[2], w3 = wr[3];
          float4 x0 = *(const float4*)&sm.xs[rg * 2 + 0][kk4 * 4];
          float4 x1 = *(const float4*)&sm.xs[rg * 2 + 1][kk4 * 4];
          acc0.x += dot4(x0, w0); acc0.y += dot4(x0, w1);
          acc0.z += dot4(x0, w2); acc0.w += dot4(x0, w3);
          acc1.x += dot4(x1, w0); acc1.y += dot4(x1, w1);
          acc1.z += dot4(x1, w2); acc1.w += dot4(x1, w3);
        }
        int lrr = lr0 + rg * 2;
        if (lrr + 0 < rows_pb) *(float4*)(Cm + (grow0 + rg * 2 + 0) * H + cg_ * 4) = acc0;
        if (lrr + 1 < rows_pb) *(float4*)(Cm + (grow0 + rg * 2 + 1) * H + cg_ * 4) = acc1;
        __syncthreads();
      } else if (u < nG + nFilm) {
        // ---- FiLM layer l -> packed bf16 (gamma lo16, beta hi16); 8 rows/unit ----
        int ru = u - nG;
        int c = t & 127, g2 = t >> 7;
        const float* fwl = p.fw + (long)l * DE * 2 * H;
        float rgw[DE], rbw[DE];
        #pragma unroll
        for (int d = 0; d < DE; d++) {
          rgw[d] = fwl[d * 2 * H + c];
          rbw[d] = fwl[d * 2 * H + H + c];
        }
        float fbg = p.fb[l * 2 * H + c], fbb = p.fb[l * 2 * H + H + c];
        int e0 = ru * 8 + g2 * 4;
        for (int e = e0; e < e0 + 4; e++) {
          if (e > E) break;
          float a[DE];
          if (e < E) {
            float4 a0 = *(const float4*)(p.ea + (long)e * DE);
            float4 a1 = *(const float4*)(p.ea + (long)e * DE + 4);
            a[0] = a0.x; a[1] = a0.y; a[2] = a0.z; a[3] = a0.w;
            a[4] = a1.x; a[5] = a1.y; a[6] = a1.z; a[7] = a1.w;
          } else {
            #pragma unroll
            for (int d = 0; d < DE; d++) a[d] = p.meanea[d] * (1.0f / E);
          }
          float g = fbg, be = fbb;
          #pragma unroll
          for (int d = 0; d < DE; d++) {
            g  += a[d] * rgw[d];
            be += a[d] * rbw[d];
          }
          unsigned int gb = __float_as_uint(g);
          gb = (gb + 0x7fffu + ((gb >> 16) & 1u)) >> 16;
          unsigned int bb_ = __float_as_uint(be);
          bb_ = (bb_ + 0x7fffu + ((bb_ >> 16) & 1u)) & 0xffff0000u;
          p.filmh[(long)e * H + c] = gb | bb_;
        }
      } else {
        // ---- CSR fill (layer 0 phase only) ----
        int f = u - nG - nFilm;
        int e = f * 256 + t;
        if (e < E) {
          int src = p.ei[e];
          int dst = p.ei[E + e];
          int pos = atomicAdd(&p.cursor[dst], 1);
          p.csr[pos] = make_int2(src, e);
        }
      }
    }
    gbar(p.bar, ++bno * GD);

    // ---- attention + O-proj + residual + LN (+ head on last layer); 2 dst/block ----
    int nout = B * (WL - out_lo) * N;
    int nA = nout >> 1;
    int last = (l == L - 1);
    for (int u = bid; u < nA; u += GD) {
      int half = t >> 7, tid = t & 127;
      int idx = u * 2 + half;
      int nwin = WL - out_lo;
      int b = idx / (nwin * N);
      int rem = idx % (nwin * N);
      int wl = out_lo + rem / N;
      int n = rem % N;
      long drow = ((long)b * WL + wl) * N + n;
      float q = p.Qb[drow * H + tid];
      long sbase = ((long)b * WL + wl) * N;
      long trow  = ((long)b * WL + wl - 1) * N + n;
      const float scale = 0.17677669529663687f;  // 1/sqrt(32)
      int i0 = p.offs[n], i1 = p.offs[n + 1];

      // temporal edge first (film row E); logits O(1) -> exp without max shift
      unsigned int fh = p.filmh[(long)E * H + tid];
      float g  = __uint_as_float(fh << 16);
      float be = __uint_as_float(fh & 0xffff0000u);
      float kv = p.Kb[trow * H + tid];
      float vv = p.Vb[trow * H + tid];
      float pp = q * (kv * (1.f + g) + be);
      float pe = __expf(headSum32(pp) * scale);
      float ssum = pe, acc = pe * vv;

      for (int i4 = i0; i4 < i1; i4 += 4) {
        #pragma unroll
        for (int j = 0; j < 4; j++) {
          int i = i4 + j;
          int ic = (i < i1) ? i : (i1 - 1);
          int2 se = p.csr[ic];
          long srow = sbase + se.x;
          unsigned int f2 = p.filmh[(long)se.y * H + tid];
          float g2 = __uint_as_float(f2 << 16);
          float b2 = __uint_as_float(f2 & 0xffff0000u);
          float kv2 = p.Kb[srow * H + tid];
          float vv2 = p.Vb[srow * H + tid];
          float p2  = q * (kv2 * (1.f + g2) + b2);
          float pe2 = __expf(headSum32(p2) * scale);
          pe2 = (i < i1) ? pe2 : 0.f;
          ssum += pe2;
          acc  += pe2 * vv2;
        }
      }
      float ab = acc / (ssum + 1e-16f);

      // O-projection via k-packed owT
      sm.at.sab[half][tid] = ab;
      __syncthreads();
      const float4* owp = (const float4*)p.wTp + (long)(l * 4 + 3) * 32 * H;
      float y = p.ob[l * H + tid];
      #pragma unroll 8
      for (int kk4 = 0; kk4 < 32; kk4++) {
        float4 w4 = owp[kk4 * H + tid];
        float4 a4 = *(const float4*)&sm.at.sab[half][kk4 * 4];
        y += dot4(a4, w4);
      }

      // residual + layernorm
      float v = xa[drow * H + tid] + y;
      float mu = halfSum(v, half, t, sm.at.red) * (1.f / H);
      float dv = v - mu;
      float var = halfSum(dv * dv, half, t, sm.at.red) * (1.f / H);
      float o = dv * rsqrtf(var + 1e-5f) * p.lng[l * H + tid] + p.lnb[l * H + tid];

      if (!last) {
        xb[drow * H + tid] = o;
      } else {
        float hv = o * p.hw[tid];
        float tot = halfSum(hv, half, t, sm.at.red);
        if (tid == 0) {
          float z = tot + p.hb[0];
          p.out[b * N + n] = fmaxf(z, 0.f) + log1pf(expf(-fabsf(z)));  // softplus
        }
      }
      __syncthreads();  // protect sab before next unit
    }
    if (l < L - 1) gbar(p.bar, ++bno * GD);
    float* tmp = xa; xa = xb; xb = tmp;
  }
}

// ---------------- launch ----------------
extern "C" void kernel_launch(void* const* d_in, const int* in_sizes, int n_in,
                              void* d_out, int out_size, void* d_ws, size_t ws_size,
                              hipStream_t stream) {
  KParams prm;
  prm.xw   = (const float*)d_in[0];
  prm.ei   = (const int*)d_in[1];
  prm.ea   = (const float*)d_in[2];
  prm.in_w = (const float*)d_in[3];
  prm.in_b = (const float*)d_in[4];
  prm.qw   = (const float*)d_in[5];
  prm.qb   = (const float*)d_in[6];
  prm.kw   = (const float*)d_in[7];
  prm.kb   = (const float*)d_in[8];
  prm.vw   = (const float*)d_in[9];
  prm.vb   = (const float*)d_in[10];
  prm.fw   = (const float*)d_in[11];
  prm.fb   = (const float*)d_in[12];
  prm.ow   = (const float*)d_in[13];
  prm.ob   = (const float*)d_in[14];
  prm.lng  = (const float*)d_in[15];
  prm.lnb  = (const float*)d_in[16];
  prm.hw   = (const float*)d_in[17];
  prm.hb   = (const float*)d_in[18];
  prm.out  = (float*)d_out;

  float* ws = (float*)d_ws;
  prm.x    = ws;
  prm.x2   = prm.x  + (long)ROWS * H;
  prm.Qb   = prm.x2 + (long)ROWS * H;
  prm.Kb   = prm.Qb + (long)ROWS * H;
  prm.Vb   = prm.Kb + (long)ROWS * H;
  prm.wTp  = prm.Vb + (long)ROWS * H;                        // 12 x 128 x 128
  prm.filmh = (unsigned int*)(prm.wTp + (long)NMAT * H * H); // (E+1) x 128 packed
  prm.meanea = (float*)(prm.filmh + (long)(E + 1) * H);      // 8 floats
  prm.bar    = (unsigned int*)(prm.meanea + 8);              // 1 uint (barrier counter)
  prm.offs   = (int*)(prm.bar + 1);
  prm.cursor = prm.offs + N + 1;
  prm.csr    = (int2*)(prm.cursor + N);

  // zero meanea (32 B) + barrier counter (4 B) in one memset
  hipMemsetAsync(prm.meanea, 0, 36, stream);
  hipLaunchKernelGGL(k_mega, dim3(GRID), dim3(256), 0, stream, prm);
}

// Round 10
// 269.114 us; speedup vs baseline: 5.3391x; 5.3391x over previous
//
#include <hip/hip_runtime.h>
#include <math.h>

// Problem constants (fixed by setup_inputs)
constexpr int B    = 2;
constexpr int W    = 16;
constexpr int N    = 1000;
constexpr int FIN  = 16;
constexpr int E    = 16000;
constexpr int DE   = 8;
constexpr int H    = 128;   // hidden
constexpr int L    = 3;
// Window pruning: temporal edges go t -> t+1 and head reads only w=15;
// 3 layers => only global windows 12..15 matter.
constexpr int WL   = 4;          // local windows kept (global 12..15)
constexpr int W0G  = 12;         // first kept global window
constexpr int RPB  = WL * N;     // rows per batch = 4000
constexpr int ROWS = B * RPB;    // 8000
constexpr int NMAT = 12;         // transposed mats: (q,k,v,o) x 3 layers
constexpr int NFILM = (E + 1 + 7) / 8;  // 2001 film units (8 edges each)

__device__ __forceinline__ float dot4(float4 a, float4 b) {
  return a.x * b.x + a.y * b.y + a.z * b.z + a.w * b.w;
}
// DPP quad-perm butterfly adds (VALU pipe, not DS)
__device__ __forceinline__ float dpp_add_xor1(float x) {
  int y = __builtin_amdgcn_update_dpp(0, __float_as_int(x), 0xB1, 0xF, 0xF, true);
  return x + __int_as_float(y);
}
__device__ __forceinline__ float dpp_add_xor2(float x) {
  int y = __builtin_amdgcn_update_dpp(0, __float_as_int(x), 0x4E, 0xF, 0xF, true);
  return x + __int_as_float(y);
}
__device__ __forceinline__ float headSum32(float p) {
  p = dpp_add_xor1(p);
  p = dpp_add_xor2(p);
  p += __shfl_xor(p, 4);
  p += __shfl_xor(p, 8);
  p += __shfl_xor(p, 16);
  return p;
}

// ================= prep: scan | weight transpose | easum | input proj =================
// One launch; all four roles are mutually independent.
__global__ void k_prep(const int* __restrict__ ei, const float* __restrict__ ea,
                       const float* __restrict__ qw, const float* __restrict__ kw,
                       const float* __restrict__ vw, const float* __restrict__ ow,
                       float4* __restrict__ wTp4,
                       const float* __restrict__ xw, const float* __restrict__ in_w,
                       const float* __restrict__ in_b, float* __restrict__ x,
                       float* __restrict__ meanea, int* __restrict__ offs,
                       int* __restrict__ cursor) {
  __shared__ union {
    struct { int cnt[1024]; int sT[256]; } sc;
    struct { float xwS[64][FIN]; float inS[FIN][H]; } ip;
    float sbuf[256];
  } sm;
  int bid = blockIdx.x;
  int t = threadIdx.x;  // 256 threads
  if (bid == 0) {
    // ---- count + scan (CSR offsets + cursor), 4-deep load batching ----
    int* cnt = sm.sc.cnt;
    for (int i = t; i < 1024; i += 256) cnt[i] = 0;
    __syncthreads();
    for (int e0 = t; e0 < E; e0 += 1024) {
      int v[4];
      #pragma unroll
      for (int j = 0; j < 4; j++) {
        int e = e0 + j * 256;
        v[j] = (e < E) ? ei[E + e] : -1;
      }
      #pragma unroll
      for (int j = 0; j < 4; j++) if (v[j] >= 0) atomicAdd(&cnt[v[j]], 1);
    }
    __syncthreads();
    int idx0 = t * 4;
    int c0 = cnt[idx0], c1 = cnt[idx0 + 1], c2 = cnt[idx0 + 2], c3 = cnt[idx0 + 3];
    int run = c0 + c1 + c2 + c3;
    int* sT = sm.sc.sT;
    sT[t] = run;
    __syncthreads();
    for (int st = 1; st < 256; st <<= 1) {
      int add = (t >= st) ? sT[t - st] : 0;
      __syncthreads();
      sT[t] += add;
      __syncthreads();
    }
    int pos = sT[t] - run;
    int cs[4] = {c0, c1, c2, c3};
    #pragma unroll
    for (int j = 0; j < 4; j++) {
      int i = idx0 + j;
      if (i < N) { offs[i + 1] = pos + cs[j]; cursor[i] = pos; }
      pos += cs[j];
    }
    if (t == 0) offs[0] = 0;
  } else if (bid < 49) {
    // ---- weight transpose into k-packed layout (48 * 1024 float4 = exact) ----
    int u0 = (bid - 1) * 1024;
    #pragma unroll
    for (int q = 0; q < 4; q++) {
      int o = u0 + q * 256 + t;
      int mat = o >> 12, rem = o & 4095;
      int kk4 = rem >> 7, c = rem & 127;
      int l = mat >> 2, mm = mat & 3;
      const float* src = ((mm == 0) ? qw : (mm == 1) ? kw : (mm == 2) ? vw : ow)
                         + (long)l * H * H;
      int k0 = kk4 * 4;
      float4 v4 = make_float4(src[(k0 + 0) * H + c], src[(k0 + 1) * H + c],
                              src[(k0 + 2) * H + c], src[(k0 + 3) * H + c]);
      wTp4[o] = v4;
    }
  } else if (bid < 81) {
    // ---- ea column sums (32 blocks) ----
    int eb = bid - 49;
    int d = t & 7, g = t >> 3;
    float s = 0.f;
    for (int e = eb * 32 + g; e < E; e += 32 * 32) s += ea[e * DE + d];
    sm.sbuf[t] = s;
    __syncthreads();
    for (int st = 16; st >= 1; st >>= 1) {
      if (g < st) sm.sbuf[g * 8 + d] += sm.sbuf[(g + st) * 8 + d];
      __syncthreads();
    }
    if (g == 0) atomicAdd(&meanea[d], sm.sbuf[d]);
  } else {
    // ---- input projection: x = xw @ in_w + in_b (64-row tiles; 126 blocks) ----
    int bi = bid - 81;
    int b = bi / 63, tt = bi % 63;
    int lr0 = tt * 64;
    for (int i = t; i < 64 * FIN; i += 256) {
      int r = i >> 4, k = i & 15;
      int lr = lr0 + r;
      float val = 0.f;
      if (lr < RPB) {
        int wl = lr / N, n = lr % N;
        val = xw[(((long)b * W + (W0G + wl)) * N + n) * FIN + k];
      }
      sm.ip.xwS[r][k] = val;
    }
    for (int i = t; i < FIN * H; i += 256) sm.ip.inS[i >> 7][i & 127] = in_w[i];
    __syncthreads();
    #pragma unroll
    for (int qi = 0; qi < 8; qi++) {
      int idx = t + qi * 256;
      int r = idx >> 5, cq = idx & 31;
      int lr = lr0 + r;
      if (lr < RPB) {
        float4 acc = *(const float4*)(in_b + cq * 4);
        #pragma unroll
        for (int k = 0; k < FIN; k++) {
          float xv = sm.ip.xwS[r][k];
          float4 w4 = *(const float4*)(&sm.ip.inS[k][cq * 4]);
          acc.x += xv * w4.x; acc.y += xv * w4.y; acc.z += xv * w4.z; acc.w += xv * w4.w;
        }
        *(float4*)(x + ((long)b * RPB + lr) * H + cq * 4) = acc;
      }
    }
  }
}

// ================= mid: QKV GEMM tiles | FiLM units | (l==0) CSR fill =================
// All roles independent; one launch per layer.
__global__ void k_mid(const float* __restrict__ X, const float4* __restrict__ wTp4,
                      int matBase,
                      const float* __restrict__ bq, const float* __restrict__ bk,
                      const float* __restrict__ bv,
                      float* __restrict__ Cq, float* __restrict__ Ck, float* __restrict__ Cv,
                      int base, int rows_pb, int tiles, int nG,
                      const float* __restrict__ ea, const float* __restrict__ fwl,
                      const float* __restrict__ fbl, const float* __restrict__ meanea,
                      unsigned int* __restrict__ filmh,
                      const int* __restrict__ ei, int* __restrict__ cursor,
                      int2* __restrict__ csr) {
  __shared__ float xs[32][H];  // 16 KB (gemm role only)
  int u = blockIdx.x;
  int t = threadIdx.x;
  if (u < nG) {
    // ---- GEMM: 32 rows x 128 cols, X in LDS, 4x4 reg tile (round-7 proven) ----
    int m = u / (B * tiles);
    int r2 = u % (B * tiles);
    int bb = r2 / tiles, tt = r2 % tiles;
    const float* bm = (m == 0) ? bq : (m == 1) ? bk : bv;
    float* Cm       = (m == 0) ? Cq : (m == 1) ? Ck : Cv;
    const float4* wp = wTp4 + (long)(matBase + m) * 32 * H;
    int lr0 = tt * 32;
    long grow0 = (long)bb * RPB + base + lr0;
    #pragma unroll
    for (int qi = 0; qi < 4; qi++) {
      int idx = t + qi * 256;
      int r = idx >> 5, c4 = idx & 31;
      float4 v4 = make_float4(0.f, 0.f, 0.f, 0.f);
      if (lr0 + r < rows_pb) v4 = *(const float4*)(X + (grow0 + r) * H + c4 * 4);
      *(float4*)&xs[r][c4 * 4] = v4;
    }
    __syncthreads();
    int cg = t & 31, rg = t >> 5;
    float4 bias4 = *(const float4*)(bm + cg * 4);
    float4 acc0 = bias4, acc1 = bias4, acc2 = bias4, acc3 = bias4;
    #pragma unroll 4
    for (int kk4 = 0; kk4 < 32; kk4++) {
      const float4* wr = wp + kk4 * H + cg * 4;
      float4 w0 = wr[0], w1 = wr[1], w2 = wr[2], w3 = wr[3];
      float4 x0 = *(const float4*)&xs[rg * 4 + 0][kk4 * 4];
      float4 x1 = *(const float4*)&xs[rg * 4 + 1][kk4 * 4];
      float4 x2 = *(const float4*)&xs[rg * 4 + 2][kk4 * 4];
      float4 x3 = *(const float4*)&xs[rg * 4 + 3][kk4 * 4];
      acc0.x += dot4(x0, w0); acc0.y += dot4(x0, w1); acc0.z += dot4(x0, w2); acc0.w += dot4(x0, w3);
      acc1.x += dot4(x1, w0); acc1.y += dot4(x1, w1); acc1.z += dot4(x1, w2); acc1.w += dot4(x1, w3);
      acc2.x += dot4(x2, w0); acc2.y += dot4(x2, w1); acc2.z += dot4(x2, w2); acc2.w += dot4(x2, w3);
      acc3.x += dot4(x3, w0); acc3.y += dot4(x3, w1); acc3.z += dot4(x3, w2); acc3.w += dot4(x3, w3);
    }
    int lrr = lr0 + rg * 4;
    if (lrr + 0 < rows_pb) *(float4*)(Cm + (grow0 + rg * 4 + 0) * H + cg * 4) = acc0;
    if (lrr + 1 < rows_pb) *(float4*)(Cm + (grow0 + rg * 4 + 1) * H + cg * 4) = acc1;
    if (lrr + 2 < rows_pb) *(float4*)(Cm + (grow0 + rg * 4 + 2) * H + cg * 4) = acc2;
    if (lrr + 3 < rows_pb) *(float4*)(Cm + (grow0 + rg * 4 + 3) * H + cg * 4) = acc3;
  } else if (u < nG + NFILM) {
    // ---- FiLM -> packed bf16 (gamma lo16, beta hi16); 8 edge-rows per block ----
    int ru = u - nG;
    int c = t & 127, g2 = t >> 7;
    float rgw[DE], rbw[DE];
    #pragma unroll
    for (int d = 0; d < DE; d++) {
      rgw[d] = fwl[d * 2 * H + c];
      rbw[d] = fwl[d * 2 * H + H + c];
    }
    float fbg = fbl[c], fbb = fbl[H + c];
    int e0 = ru * 8 + g2 * 4;
    for (int e = e0; e < e0 + 4; e++) {
      if (e > E) break;
      float a[DE];
      if (e < E) {
        float4 a0 = *(const float4*)(ea + (long)e * DE);
        float4 a1 = *(const float4*)(ea + (long)e * DE + 4);
        a[0] = a0.x; a[1] = a0.y; a[2] = a0.z; a[3] = a0.w;
        a[4] = a1.x; a[5] = a1.y; a[6] = a1.z; a[7] = a1.w;
      } else {
        #pragma unroll
        for (int d = 0; d < DE; d++) a[d] = meanea[d] * (1.0f / E);
      }
      float g = fbg, be = fbb;
      #pragma unroll
      for (int d = 0; d < DE; d++) {
        g  += a[d] * rgw[d];
        be += a[d] * rbw[d];
      }
      unsigned int gb = __float_as_uint(g);
      gb = (gb + 0x7fffu + ((gb >> 16) & 1u)) >> 16;
      unsigned int bb_ = __float_as_uint(be);
      bb_ = (bb_ + 0x7fffu + ((bb_ >> 16) & 1u)) & 0xffff0000u;
      filmh[(long)e * H + c] = gb | bb_;
    }
  } else {
    // ---- CSR fill (layer-0 launch only) ----
    int f = u - nG - NFILM;
    int e = f * 256 + t;
    if (e < E) {
      int src = ei[e];
      int dst = ei[E + e];
      int pos = atomicAdd(&cursor[dst], 1);
      csr[pos] = make_int2(src, e);
    }
  }
}

// ======= attn (gather, no-max softmax, bf16-film, 4-edge ILP) + O-proj + LN =======
// 2 destination rows per 256-thread block (validated in r9 mega kernel).
__global__ void k_attn_oln(const float* __restrict__ Qb, const float* __restrict__ Kb,
                           const float* __restrict__ Vb,
                           const unsigned int* __restrict__ filmh,
                           const int* __restrict__ offs, const int2* __restrict__ csr,
                           const float* __restrict__ x, const float4* __restrict__ owp,
                           const float* __restrict__ ob, const float* __restrict__ lng,
                           const float* __restrict__ lnb, float* __restrict__ xo,
                           int out_lo,
                           const float* __restrict__ hw, const float* __restrict__ hb,
                           float* __restrict__ out, int do_head) {
  __shared__ float sab[2][H];
  __shared__ float red[2][2];
  int t = threadIdx.x;
  int half = t >> 7, tid = t & 127;
  int idx = blockIdx.x * 2 + half;
  int nwin = WL - out_lo;
  int b = idx / (nwin * N);
  int rem = idx % (nwin * N);
  int wl = out_lo + rem / N;
  int n = rem % N;
  long drow = ((long)b * WL + wl) * N + n;
  float q = Qb[drow * H + tid];
  long sbase = ((long)b * WL + wl) * N;
  long trow  = ((long)b * WL + wl - 1) * N + n;
  const float scale = 0.17677669529663687f;  // 1/sqrt(32)
  int i0 = offs[n], i1 = offs[n + 1];

  // temporal edge first (film row E); logits O(1) -> exp without max shift
  unsigned int fh = filmh[(long)E * H + tid];
  float g  = __uint_as_float(fh << 16);
  float be = __uint_as_float(fh & 0xffff0000u);
  float kv = Kb[trow * H + tid];
  float vv = Vb[trow * H + tid];
  float pp = q * (kv * (1.f + g) + be);
  float pe = __expf(headSum32(pp) * scale);
  float ssum = pe, acc = pe * vv;

  for (int i4 = i0; i4 < i1; i4 += 4) {
    #pragma unroll
    for (int j = 0; j < 4; j++) {
      int i = i4 + j;
      int ic = (i < i1) ? i : (i1 - 1);
      int2 se = csr[ic];
      long srow = sbase + se.x;
      unsigned int f2 = filmh[(long)se.y * H + tid];
      float g2 = __uint_as_float(f2 << 16);
      float b2 = __uint_as_float(f2 & 0xffff0000u);
      float kv2 = Kb[srow * H + tid];
      float vv2 = Vb[srow * H + tid];
      float p2  = q * (kv2 * (1.f + g2) + b2);
      float pe2 = __expf(headSum32(p2) * scale);
      pe2 = (i < i1) ? pe2 : 0.f;
      ssum += pe2;
      acc  += pe2 * vv2;
    }
  }
  float ab = acc / (ssum + 1e-16f);

  // O-projection via k-packed owT
  sab[half][tid] = ab;
  __syncthreads();
  float y = ob[tid];
  #pragma unroll 8
  for (int kk4 = 0; kk4 < 32; kk4++) {
    float4 w4 = owp[kk4 * H + tid];
    float4 a4 = *(const float4*)&sab[half][kk4 * 4];
    y += dot4(a4, w4);
  }

  // residual + layernorm (halfSum: reduce within each 128-thread half)
  float v = x[drow * H + tid] + y;
  #pragma unroll
  for (int off = 32; off >= 1; off >>= 1) v += 0.f;  // (placeholder removed below)
  // mean
  float s = x[drow * H + tid] + y;
  float r1 = s;
  #pragma unroll
  for (int off = 32; off >= 1; off >>= 1) r1 += __shfl_xor(r1, off);
  {
    int w = (t >> 6) & 1;
    __syncthreads();
    if ((t & 63) == 0) red[half][w] = r1;
    __syncthreads();
  }
  float mu = (red[half][0] + red[half][1]) * (1.f / H);
  float dv = s - mu;
  float r2v = dv * dv;
  #pragma unroll
  for (int off = 32; off >= 1; off >>= 1) r2v += __shfl_xor(r2v, off);
  {
    int w = (t >> 6) & 1;
    __syncthreads();
    if ((t & 63) == 0) red[half][w] = r2v;
    __syncthreads();
  }
  float var = (red[half][0] + red[half][1]) * (1.f / H);
  float o = dv * rsqrtf(var + 1e-5f) * lng[tid] + lnb[tid];

  if (!do_head) {
    xo[drow * H + tid] = o;
  } else {
    float hv = o * hw[tid];
    float r3 = hv;
    #pragma unroll
    for (int off = 32; off >= 1; off >>= 1) r3 += __shfl_xor(r3, off);
    int w = (t >> 6) & 1;
    __syncthreads();
    if ((t & 63) == 0) red[half][w] = r3;
    __syncthreads();
    if (tid == 0) {
      float z = red[half][0] + red[half][1] + hb[0];
      out[b * N + n] = fmaxf(z, 0.f) + log1pf(expf(-fabsf(z)));  // softplus
    }
  }
}

// ---------------- launch ----------------
extern "C" void kernel_launch(void* const* d_in, const int* in_sizes, int n_in,
                              void* d_out, int out_size, void* d_ws, size_t ws_size,
                              hipStream_t stream) {
  const float* xw   = (const float*)d_in[0];
  const int*   ei   = (const int*)d_in[1];
  const float* ea   = (const float*)d_in[2];
  const float* in_w = (const float*)d_in[3];
  const float* in_b = (const float*)d_in[4];
  const float* qw   = (const float*)d_in[5];
  const float* qb   = (const float*)d_in[6];
  const float* kw   = (const float*)d_in[7];
  const float* kb   = (const float*)d_in[8];
  const float* vw   = (const float*)d_in[9];
  const float* vb   = (const float*)d_in[10];
  const float* fw   = (const float*)d_in[11];
  const float* fb   = (const float*)d_in[12];
  const float* ow   = (const float*)d_in[13];
  const float* ob   = (const float*)d_in[14];
  const float* ln_g = (const float*)d_in[15];
  const float* ln_b = (const float*)d_in[16];
  const float* hw   = (const float*)d_in[17];
  const float* hb   = (const float*)d_in[18];
  float* out = (float*)d_out;

  // workspace carve-up (16B-aligned chunks first)
  float* ws   = (float*)d_ws;
  float* x    = ws;
  float* x2   = x  + (long)ROWS * H;
  float* Qb   = x2 + (long)ROWS * H;
  float* Kb   = Qb + (long)ROWS * H;
  float* Vb   = Kb + (long)ROWS * H;
  float* wTp  = Vb + (long)ROWS * H;                        // 12 x 128 x 128
  unsigned int* filmh = (unsigned int*)(wTp + (long)NMAT * H * H);  // (E+1) x 128
  float* meanea = (float*)(filmh + (long)(E + 1) * H);      // 8 floats
  int* offs    = (int*)(meanea + 8);
  int* cursor  = offs + N + 1;
  int2* csr    = (int2*)(cursor + N);
  float4* wTp4 = (float4*)wTp;

  hipMemsetAsync(meanea, 0, 8 * sizeof(float), stream);
  k_prep<<<207, 256, 0, stream>>>(ei, ea, qw, kw, vw, ow, wTp4,
                                  xw, in_w, in_b, x, meanea, offs, cursor);

  float* xa = x;
  float* xb = x2;
  for (int l = 0; l < L; l++) {
    int out_lo = l + 1;
    int rows_pb = (WL - l) * N;
    int tiles = (rows_pb + 31) / 32;
    int nG = 3 * B * tiles;
    int nFill = (l == 0) ? (E + 255) / 256 : 0;
    int nMid = nG + NFILM + nFill;
    k_mid<<<nMid, 256, 0, stream>>>(
        xa, wTp4, l * 4, qb + (long)l * H, kb + (long)l * H, vb + (long)l * H,
        Qb, Kb, Vb, l * N, rows_pb, tiles, nG,
        ea, fw + (long)l * DE * 2 * H, fb + (long)l * 2 * H, meanea, filmh,
        ei, cursor, csr);
    int nout = B * (WL - out_lo) * N;
    int last = (l == L - 1) ? 1 : 0;
    k_attn_oln<<<nout / 2, 256, 0, stream>>>(
        Qb, Kb, Vb, filmh, offs, csr,
        xa, wTp4 + ((long)l * 4 + 3) * 32 * H, ob + (long)l * H,
        ln_g + (long)l * H, ln_b + (long)l * H, xb, out_lo,
        hw, hb, out, last);
    float* tmp = xa; xa = xb; xb = tmp;
  }
}